// Round 7
// baseline (202.989 us; speedup 1.0000x reference)
//
#include <hip/hip_runtime.h>
#include <hip/hip_fp16.h>

#define N_NODES 8192
#define F_IN    512
#define F_OUT   256
#define LOG2E   1.4426950408889634f

typedef __attribute__((ext_vector_type(8))) _Float16 half8;
typedef __attribute__((ext_vector_type(2))) __fp16   fp16x2;
typedef __attribute__((ext_vector_type(4))) float    f32x4;
typedef __attribute__((ext_vector_type(4))) int      i32x4;

union H8U4 { half8 h; uint4 u; };
union H2U  { fp16x2 h; unsigned u; };

// ---------------------------------------------------------------------------
// k_prep: (a) init emax; (b) pack W into f16 hi/lo B-fragment layout
// (same layout as hpack). hi=f16(w), lo=f16(w-hi): 3-term f16 MFMA emulates
// fp32 GEMM to ~2^-20.
// ---------------------------------------------------------------------------
__global__ __launch_bounds__(256) void k_prep(const float* __restrict__ W,
                                              unsigned short* __restrict__ wph,
                                              unsigned short* __restrict__ wpl,
                                              unsigned* __restrict__ emax_u) {
  const int gid = blockIdx.x * 256 + threadIdx.x;   // 512 blocks -> 131072
  if (gid == 0) *emax_u = 0u;
  const int k = gid >> 8;          // 0..511
  const int c = gid & 255;         // 0..255
  const float w = W[(size_t)k * F_OUT + c];
  const _Float16 hi = (_Float16)w;
  const _Float16 lo = (_Float16)(w - (float)hi);
  const size_t idx =
      (((size_t)(k >> 5) * 16 + (c >> 4)) * 64 + (c & 15) + 16 * ((k >> 3) & 3)) * 8 +
      (k & 7);
  wph[idx] = *(const unsigned short*)&hi;
  wpl[idx] = *(const unsigned short*)&lo;
}

// ---------------------------------------------------------------------------
// k_hgemm (r9, proven): h = x@W via split-f16 MFMA. Unchanged this round.
// ---------------------------------------------------------------------------
__global__ __launch_bounds__(512) void k_hgemm(const float* __restrict__ x,
                                               const uint4* __restrict__ wph4,
                                               const uint4* __restrict__ wpl4,
                                               const float* __restrict__ a,
                                               unsigned short* __restrict__ hpack,
                                               float* __restrict__ EI,
                                               float* __restrict__ EJ,
                                               unsigned* __restrict__ emax_u) {
  __shared__ float eip[4][32], ejp[4][32], emx[32];
  const int r0   = blockIdx.x * 32;
  const int tid  = threadIdx.x;
  const int wid  = tid >> 6, lane = tid & 63;
  const int mg   = wid >> 2, ng = wid & 3;      // 2 row-groups x 4 col-groups
  const int lo16 = lane & 15, hi4 = lane >> 4;

  const float* xrow = x + (size_t)(r0 + mg * 16 + lo16) * F_IN + hi4 * 8;
  const uint4* whb = wph4 + (size_t)(ng * 4) * 64 + lane;  // + (ks*16+nf)*64
  const uint4* wlb = wpl4 + (size_t)(ng * 4) * 64 + lane;

  f32x4 acc[4] = {};

  float4 xa = *(const float4*)(xrow);
  float4 xb = *(const float4*)(xrow + 4);
  uint4 wh[4], wl[4];
#pragma unroll
  for (int nf = 0; nf < 4; ++nf) {
    wh[nf] = whb[(size_t)nf * 64];
    wl[nf] = wlb[(size_t)nf * 64];
  }

#pragma unroll
  for (int ks = 0; ks < 16; ++ks) {
    H8U4 ah, al;
    const float v[8] = {xa.x, xa.y, xa.z, xa.w, xb.x, xb.y, xb.z, xb.w};
#pragma unroll
    for (int j = 0; j < 8; ++j) {
      const _Float16 h = (_Float16)v[j];
      ah.h[j] = h;
      al.h[j] = (_Float16)(v[j] - (float)h);
    }
    if (ks + 1 < 16) {
      xa = *(const float4*)(xrow + (ks + 1) * 32);
      xb = *(const float4*)(xrow + (ks + 1) * 32 + 4);
    }
#pragma unroll
    for (int nf = 0; nf < 4; ++nf) {
      H8U4 bh, bl;
      bh.u = wh[nf];
      bl.u = wl[nf];
      acc[nf] = __builtin_amdgcn_mfma_f32_16x16x32_f16(ah.h, bh.h, acc[nf], 0, 0, 0);
      acc[nf] = __builtin_amdgcn_mfma_f32_16x16x32_f16(al.h, bh.h, acc[nf], 0, 0, 0);
      acc[nf] = __builtin_amdgcn_mfma_f32_16x16x32_f16(ah.h, bl.h, acc[nf], 0, 0, 0);
    }
    if (ks + 1 < 16) {
#pragma unroll
      for (int nf = 0; nf < 4; ++nf) {
        wh[nf] = whb[(size_t)((ks + 1) * 16 + nf) * 64];
        wl[nf] = wlb[(size_t)((ks + 1) * 16 + nf) * 64];
      }
    }
  }

  float asv[4], adv[4];
#pragma unroll
  for (int nf = 0; nf < 4; ++nf) {
    const int c = ng * 64 + nf * 16 + lo16;
    asv[nf] = a[c];
    adv[nf] = a[F_OUT + c];
  }
#pragma unroll
  for (int q = 0; q < 4; ++q) {
    float s1 = acc[0][q] * asv[0] + acc[1][q] * asv[1] + acc[2][q] * asv[2] +
               acc[3][q] * asv[3];
    float s2 = acc[0][q] * adv[0] + acc[1][q] * adv[1] + acc[2][q] * adv[2] +
               acc[3][q] * adv[3];
#pragma unroll
    for (int o = 1; o < 16; o <<= 1) {
      s1 += __shfl_xor(s1, o);
      s2 += __shfl_xor(s2, o);
    }
    if (lo16 == 0) {
      const int rl = mg * 16 + hi4 * 4 + q;
      eip[ng][rl] = s1;
      ejp[ng][rl] = s2;
    }
  }

#pragma unroll
  for (int nf = 0; nf < 4; ++nf) {
#pragma unroll
    for (int q = 0; q < 4; ++q) {
      const int row = r0 + mg * 16 + hi4 * 4 + q;
      const int col = ng * 64 + nf * 16 + lo16;
      const size_t idx =
          (((size_t)(row >> 5) * 16 + (col >> 4)) * 64 + (col & 15) +
           16 * ((row >> 3) & 3)) * 8 + (row & 7);
      const _Float16 hv = (_Float16)acc[nf][q];
      hpack[idx] = *(const unsigned short*)&hv;
    }
  }

  __syncthreads();
  if (tid < 32) {
    const float s1 = eip[0][tid] + eip[1][tid] + eip[2][tid] + eip[3][tid];
    const float s2 = ejp[0][tid] + ejp[1][tid] + ejp[2][tid] + ejp[3][tid];
    const int row = r0 + tid;
    EI[row] = s1 * LOG2E;
    const float e2 = s2 * LOG2E;
    EJ[row] = e2;
    emx[tid] = e2;
  }
  __syncthreads();
  if (tid == 0) {
    float m = emx[0];
#pragma unroll
    for (int i = 1; i < 32; ++i) m = fmaxf(m, emx[i]);
    unsigned b = __float_as_uint(m);
    unsigned u = (b & 0x80000000u) ? ~b : (b | 0x80000000u);
    atomicMax(emax_u, u);
  }
}

// ---------------------------------------------------------------------------
// k_pv r14: KVBLK 64 -> 128 (j-tile doubling). Same proven 2-barrier skeleton
// and fragment math as r12, but HALF the pipeline turns: 16 tiles/block, each
// {P(16 vals/thread, 2 ps4 slots) -> bar -> ds-drain -> bar -> 32 MFMA}.
// Fused adj->mask staging kept: per thread 4 i32x4 (512B/row wave segments),
// 2 mask bytes -> bml; depth-2 tile prefetch. B in two 8-reg batches (ksw0/1
// at tile top, ksw2/3 after barrier-2) to respect the 128-VGPR cap. ejlo
// computed in-flight (LDS ~27KB). nsplit reverted to 4 (R6: 8 hurt).
// ---------------------------------------------------------------------------
__global__ __launch_bounds__(512, 4) void k_pv(const int* __restrict__ adj,
                                               const uint4* __restrict__ hp4,
                                               const float* __restrict__ EI,
                                               const float* __restrict__ EJ,
                                               const unsigned* __restrict__ emax_u,
                                               float* __restrict__ npart,
                                               float* __restrict__ dpart,
                                               int ntiles) {
  __shared__ __align__(16) uint4 ps4[16 * 64];  // 16 KB P tile (A-frag layout)
  __shared__ float ejhi[2048];                  // split's EJ (<= 16 tiles x 128)
  __shared__ float A1[64], A2[64], den[64];
  __shared__ unsigned char bml[2][1024];        // double-buffered mask bytes
  const int rowbase = blockIdx.x * 64;
  const int split   = blockIdx.y;
  const int jt0     = split * ntiles;           // in 128-wide tile units
  const int tid     = threadIdx.x;
  const int wid  = tid >> 6, lane = tid & 63;
  const int lo   = lane & 15, hi = lane >> 4;

  float EMAX;
  {
    const unsigned u = *emax_u;
    EMAX = (u & 0x80000000u) ? __uint_as_float(u & 0x7fffffffu) : __uint_as_float(~u);
  }
  if (tid < 64) {
    const float e  = EI[rowbase + tid];
    const float s  = e + EMAX;
    const float mi = fmaxf(s, 0.2f * s);
    A1[tid] = e - mi;
    A2[tid] = 0.2f * e - mi;
    den[tid] = 0.f;
  }
  const bool uselds = (ntiles <= 16);
  if (uselds) {
    int eidx = jt0 * 128 + tid * 4;
    if (eidx > N_NODES - 4) eidx = N_NODES - 4;
    *(float4*)&ejhi[tid * 4] = *(const float4*)&EJ[eidx];
  }

  // ---- adj staging role: thread -> (row = tid>>3, 16-col group = tid&7) ----
  const int arow = tid >> 3, ac8 = tid & 7;
  const int* aadj = adj + (size_t)(rowbase + arow) * N_NODES + jt0 * 128 + ac8 * 16;
  // Prologue: pack tile 0 into bml[0]; preload tile 1 into regs.
  {
    const i32x4 v0 = __builtin_nontemporal_load((const i32x4*)(aadj));
    const i32x4 v1 = __builtin_nontemporal_load((const i32x4*)(aadj + 4));
    const i32x4 v2 = __builtin_nontemporal_load((const i32x4*)(aadj + 8));
    const i32x4 v3 = __builtin_nontemporal_load((const i32x4*)(aadj + 12));
    unsigned by0 = (v0.x > 0) | ((v0.y > 0) << 1) | ((v0.z > 0) << 2) |
                   ((v0.w > 0) << 3) | ((v1.x > 0) << 4) | ((v1.y > 0) << 5) |
                   ((v1.z > 0) << 6) | ((v1.w > 0) << 7);
    unsigned by1 = (v2.x > 0) | ((v2.y > 0) << 1) | ((v2.z > 0) << 2) |
                   ((v2.w > 0) << 3) | ((v3.x > 0) << 4) | ((v3.y > 0) << 5) |
                   ((v3.z > 0) << 6) | ((v3.w > 0) << 7);
    *(unsigned short*)&bml[0][arow * 16 + ac8 * 2] =
        (unsigned short)(by0 | (by1 << 8));
  }
  i32x4 av0 = {0,0,0,0}, av1 = {0,0,0,0}, av2 = {0,0,0,0}, av3 = {0,0,0,0};
  if (ntiles > 1) {
    av0 = __builtin_nontemporal_load((const i32x4*)(aadj + 128));
    av1 = __builtin_nontemporal_load((const i32x4*)(aadj + 132));
    av2 = __builtin_nontemporal_load((const i32x4*)(aadj + 136));
    av3 = __builtin_nontemporal_load((const i32x4*)(aadj + 140));
  }
  __syncthreads();   // A1/A2, ejhi, bml[0] ready

  // P-writer role: thread owns ps4 slots wid (j-half 0) and wid+8 (j-half 1).
  const int msub = wid & 3, ksw0 = wid >> 2;      // ksw0 in {0,1}
  const int row_p = msub * 16 + lo;
  const int jloc  = ksw0 * 32 + hi * 8;           // j offset within 64-half
  const float a1r = A1[row_p], a2r = A2[row_p];
  const int  mbidx = row_p * 16 + ksw0 * 4 + hi;  // byte idx (half 0); +8 half 1
  const float* ejg = EJ + jt0 * 128 + jloc;       // fallback path
  // MFMA-reader role: wave (mg,ng) owns rows [mg*32,+32) x cols [ng*64,+64).
  const int mg = wid >> 2, ng = wid & 3;
  const uint4* hb = hp4 + (ng * 4) * 64 + lane;

  f32x4 acc[2][4] = {};
  float dacc = 0.f;

  for (int jt = 0; jt < ntiles; ++jt) {
    const int tb = (jt0 + jt) * 4096;  // uint4 offset: 4 k-blocks per 128-tile
    // B batch 1: k-blocks 0,1 (latency covered by whole P phase).
    uint4 b0[4], b1[4];
#pragma unroll
    for (int f = 0; f < 4; ++f) {
      b0[f] = hb[tb + 0 * 1024 + f * 64];
      b1[f] = hb[tb + 1 * 1024 + f * 64];
    }

    // ---- P compute: 16 values/thread (j-halves 0 and 1) ----
    const unsigned mb0 = bml[jt & 1][mbidx];
    const unsigned mb1 = bml[jt & 1][mbidx + 8];
    float eh[16];
    if (uselds) {
      const float4 h0 = *(const float4*)&ejhi[jt * 128 + jloc];
      const float4 h1 = *(const float4*)&ejhi[jt * 128 + jloc + 4];
      const float4 h2 = *(const float4*)&ejhi[jt * 128 + jloc + 64];
      const float4 h3 = *(const float4*)&ejhi[jt * 128 + jloc + 68];
      eh[0]=h0.x; eh[1]=h0.y; eh[2]=h0.z; eh[3]=h0.w;
      eh[4]=h1.x; eh[5]=h1.y; eh[6]=h1.z; eh[7]=h1.w;
      eh[8]=h2.x; eh[9]=h2.y; eh[10]=h2.z; eh[11]=h2.w;
      eh[12]=h3.x; eh[13]=h3.y; eh[14]=h3.z; eh[15]=h3.w;
    } else {
      const float4 h0 = *(const float4*)(ejg + jt * 128);
      const float4 h1 = *(const float4*)(ejg + jt * 128 + 4);
      const float4 h2 = *(const float4*)(ejg + jt * 128 + 64);
      const float4 h3 = *(const float4*)(ejg + jt * 128 + 68);
      eh[0]=h0.x; eh[1]=h0.y; eh[2]=h0.z; eh[3]=h0.w;
      eh[4]=h1.x; eh[5]=h1.y; eh[6]=h1.z; eh[7]=h1.w;
      eh[8]=h2.x; eh[9]=h2.y; eh[10]=h2.z; eh[11]=h2.w;
      eh[12]=h3.x; eh[13]=h3.y; eh[14]=h3.z; eh[15]=h3.w;
    }
    float ph[16];
#pragma unroll
    for (int j = 0; j < 8; ++j) {
      const float s = fmaxf(eh[j] + a1r, 0.2f * eh[j] + a2r);
      const float p = __builtin_amdgcn_exp2f(s);
      ph[j] = (mb0 & (1u << j)) ? p : 0.f;
    }
#pragma unroll
    for (int j = 8; j < 16; ++j) {
      const float s = fmaxf(eh[j] + a1r, 0.2f * eh[j] + a2r);
      const float p = __builtin_amdgcn_exp2f(s);
      ph[j] = (mb1 & (1u << (j - 8))) ? p : 0.f;
    }
#pragma unroll
    for (int j = 0; j < 16; ++j) dacc += ph[j];
    H2U q0, q1, q2, q3, q4, q5, q6, q7;
    q0.h = __builtin_amdgcn_cvt_pkrtz(ph[0], ph[1]);
    q1.h = __builtin_amdgcn_cvt_pkrtz(ph[2], ph[3]);
    q2.h = __builtin_amdgcn_cvt_pkrtz(ph[4], ph[5]);
    q3.h = __builtin_amdgcn_cvt_pkrtz(ph[6], ph[7]);
    q4.h = __builtin_amdgcn_cvt_pkrtz(ph[8], ph[9]);
    q5.h = __builtin_amdgcn_cvt_pkrtz(ph[10], ph[11]);
    q6.h = __builtin_amdgcn_cvt_pkrtz(ph[12], ph[13]);
    q7.h = __builtin_amdgcn_cvt_pkrtz(ph[14], ph[15]);
    uint4 pk0 = {q0.u, q1.u, q2.u, q3.u};
    uint4 pk1 = {q4.u, q5.u, q6.u, q7.u};

    asm volatile("" ::: "memory");
    __builtin_amdgcn_s_barrier();        // all waves done reading ps4 (prev tile)
    asm volatile("" ::: "memory");
    ps4[wid * 64 + lane]       = pk0;    // slot (ksw0, msub)
    ps4[(wid + 8) * 64 + lane] = pk1;    // slot (ksw0+2, msub)
    // Pack mask bytes for tile jt+1 (regs from last window); issue coalesced
    // NT loads for tile jt+2 (two full phases of latency cover).
    if (jt + 1 < ntiles) {
      unsigned by0 = (av0.x > 0) | ((av0.y > 0) << 1) | ((av0.z > 0) << 2) |
                     ((av0.w > 0) << 3) | ((av1.x > 0) << 4) | ((av1.y > 0) << 5) |
                     ((av1.z > 0) << 6) | ((av1.w > 0) << 7);
      unsigned by1 = (av2.x > 0) | ((av2.y > 0) << 1) | ((av2.z > 0) << 2) |
                     ((av2.w > 0) << 3) | ((av3.x > 0) << 4) | ((av3.y > 0) << 5) |
                     ((av3.z > 0) << 6) | ((av3.w > 0) << 7);
      *(unsigned short*)&bml[(jt + 1) & 1][arow * 16 + ac8 * 2] =
          (unsigned short)(by0 | (by1 << 8));
      if (jt + 2 < ntiles) {
        const int* ap = aadj + (jt + 2) * 128;
        av0 = __builtin_nontemporal_load((const i32x4*)(ap));
        av1 = __builtin_nontemporal_load((const i32x4*)(ap + 4));
        av2 = __builtin_nontemporal_load((const i32x4*)(ap + 8));
        av3 = __builtin_nontemporal_load((const i32x4*)(ap + 12));
      }
    }
    asm volatile("s_waitcnt lgkmcnt(0)" ::: "memory");  // ps4 + bml writes visible
    __builtin_amdgcn_s_barrier();        // P tile ready
    asm volatile("" ::: "memory");

    // B batch 2: k-blocks 2,3 (covered by A reads + first MFMAs + TLP).
    uint4 b2[4], b3[4];
#pragma unroll
    for (int f = 0; f < 4; ++f) {
      b2[f] = hb[tb + 2 * 1024 + f * 64];
      b3[f] = hb[tb + 3 * 1024 + f * 64];
    }

    H8U4 a0, a1, b;
    __builtin_amdgcn_s_setprio(1);
    a0.u = ps4[(0 * 4 + mg * 2 + 0) * 64 + lane];
    a1.u = ps4[(0 * 4 + mg * 2 + 1) * 64 + lane];
#pragma unroll
    for (int f = 0; f < 4; ++f) {
      b.u = b0[f];
      acc[0][f] = __builtin_amdgcn_mfma_f32_16x16x32_f16(a0.h, b.h, acc[0][f], 0, 0, 0);
      acc[1][f] = __builtin_amdgcn_mfma_f32_16x16x32_f16(a1.h, b.h, acc[1][f], 0, 0, 0);
    }
    a0.u = ps4[(1 * 4 + mg * 2 + 0) * 64 + lane];
    a1.u = ps4[(1 * 4 + mg * 2 + 1) * 64 + lane];
#pragma unroll
    for (int f = 0; f < 4; ++f) {
      b.u = b1[f];
      acc[0][f] = __builtin_amdgcn_mfma_f32_16x16x32_f16(a0.h, b.h, acc[0][f], 0, 0, 0);
      acc[1][f] = __builtin_amdgcn_mfma_f32_16x16x32_f16(a1.h, b.h, acc[1][f], 0, 0, 0);
    }
    a0.u = ps4[(2 * 4 + mg * 2 + 0) * 64 + lane];
    a1.u = ps4[(2 * 4 + mg * 2 + 1) * 64 + lane];
#pragma unroll
    for (int f = 0; f < 4; ++f) {
      b.u = b2[f];
      acc[0][f] = __builtin_amdgcn_mfma_f32_16x16x32_f16(a0.h, b.h, acc[0][f], 0, 0, 0);
      acc[1][f] = __builtin_amdgcn_mfma_f32_16x16x32_f16(a1.h, b.h, acc[1][f], 0, 0, 0);
    }
    a0.u = ps4[(3 * 4 + mg * 2 + 0) * 64 + lane];
    a1.u = ps4[(3 * 4 + mg * 2 + 1) * 64 + lane];
#pragma unroll
    for (int f = 0; f < 4; ++f) {
      b.u = b3[f];
      acc[0][f] = __builtin_amdgcn_mfma_f32_16x16x32_f16(a0.h, b.h, acc[0][f], 0, 0, 0);
      acc[1][f] = __builtin_amdgcn_mfma_f32_16x16x32_f16(a1.h, b.h, acc[1][f], 0, 0, 0);
    }
    __builtin_amdgcn_s_setprio(0);
  }

  atomicAdd(&den[row_p], dacc);
  __syncthreads();

  float* npb = npart + (size_t)split * N_NODES * F_OUT;
#pragma unroll
  for (int mi_ = 0; mi_ < 2; ++mi_) {
    const int rb = rowbase + (mg * 2 + mi_) * 16 + hi * 4;
#pragma unroll
    for (int nf = 0; nf < 4; ++nf) {
      const int col = ng * 64 + nf * 16 + lo;
#pragma unroll
      for (int r2 = 0; r2 < 4; ++r2)
        __builtin_nontemporal_store(acc[mi_][nf][r2],
                                    &npb[(size_t)(rb + r2) * F_OUT + col]);
    }
  }
  if (tid < 64)
    __builtin_nontemporal_store(den[tid],
                                &dpart[(size_t)split * N_NODES + rowbase + tid]);
}

// ---------------------------------------------------------------------------
// k_fin: combine splits, divide by denom, ELU, write output.
// ---------------------------------------------------------------------------
__global__ __launch_bounds__(256) void k_fin(const float* __restrict__ npart,
                                             const float* __restrict__ dpart,
                                             float* __restrict__ out,
                                             int nsplit) {
  const int gid = blockIdx.x * 256 + threadIdx.x;
  const int row = gid >> 6;
  const int c4  = (gid & 63) << 2;
  f32x4 s = {0.f, 0.f, 0.f, 0.f};
  float d = 0.f;
  for (int sp = 0; sp < nsplit; ++sp) {
    const f32x4 v = __builtin_nontemporal_load(
        (const f32x4*)(npart + ((size_t)sp * N_NODES + row) * F_OUT + c4));
    s += v;
    d += dpart[(size_t)sp * N_NODES + row];
  }
  const float inv = 1.f / d;
  float o[4] = {s.x * inv, s.y * inv, s.z * inv, s.w * inv};
#pragma unroll
  for (int i = 0; i < 4; ++i) o[i] = (o[i] > 0.f) ? o[i] : expm1f(o[i]);
  float4 ov = {o[0], o[1], o[2], o[3]};
  *(float4*)(out + (size_t)row * F_OUT + c4) = ov;
}

// ---------------------------------------------------------------------------
extern "C" void kernel_launch(void* const* d_in, const int* in_sizes, int n_in,
                              void* d_out, int out_size, void* d_ws, size_t ws_size,
                              hipStream_t stream) {
  const float* x   = (const float*)d_in[0];
  const int*   adj = (const int*)d_in[1];
  const float* W   = (const float*)d_in[2];
  const float* a   = (const float*)d_in[3];
  float* out = (float*)d_out;
  char*  ws  = (char*)d_ws;

  unsigned short* hpack = (unsigned short*)ws;  // 4 MB, B-fragment layout
  size_t off = (size_t)4 * 1024 * 1024;
  float* EI = (float*)(ws + off); off += (size_t)N_NODES * 4;
  float* EJ = (float*)(ws + off); off += (size_t)N_NODES * 4;
  unsigned* emax_u = (unsigned*)(ws + off); off += 256;
  float* dpart = (float*)(ws + off); off += (size_t)8 * N_NODES * 4;
  unsigned short* wph = (unsigned short*)(ws + off); off += (size_t)F_IN * F_OUT * 2;
  unsigned short* wpl = (unsigned short*)(ws + off); off += (size_t)F_IN * F_OUT * 2;
  float* npart = (float*)(ws + off);

  // r14: nsplit back to 4 (proven best, R6 showed 8 hurts); 128-wide j-tiles
  // -> ntiles = (8192/128)/nsplit = 16 per block.
  int nsplit = 4;
  while (nsplit > 1 && off + (size_t)nsplit * N_NODES * F_OUT * 4 > ws_size) nsplit >>= 1;

  k_prep<<<dim3((F_IN * F_OUT) / 256), dim3(256), 0, stream>>>(W, wph, wpl, emax_u);
  k_hgemm<<<dim3(N_NODES / 32), dim3(512), 0, stream>>>(
      x, (const uint4*)wph, (const uint4*)wpl, a, hpack, EI, EJ, emax_u);
  k_pv<<<dim3(128, nsplit), dim3(512), 0, stream>>>(adj, (const uint4*)hpack, EI, EJ,
                                                    emax_u, npart, dpart,
                                                    (N_NODES / 128) / nsplit);
  k_fin<<<dim3(N_NODES * 64 / 256), dim3(256), 0, stream>>>(npart, dpart, out, nsplit);
}

// Round 8
// 192.031 us; speedup vs baseline: 1.0571x; 1.0571x over previous
//
#include <hip/hip_runtime.h>
#include <hip/hip_fp16.h>

#define N_NODES 8192
#define F_IN    512
#define F_OUT   256
#define LOG2E   1.4426950408889634f

typedef __attribute__((ext_vector_type(8))) _Float16 half8;
typedef __attribute__((ext_vector_type(2))) __fp16   fp16x2;
typedef __attribute__((ext_vector_type(4))) float    f32x4;
typedef __attribute__((ext_vector_type(4))) int      i32x4;

union H8U4 { half8 h; uint4 u; };
union H2U  { fp16x2 h; unsigned u; };

// ---------------------------------------------------------------------------
// k_prep: (a) init emax; (b) pack W into f16 hi/lo B-fragment layout
// (same layout as hpack). hi=f16(w), lo=f16(w-hi): 3-term f16 MFMA emulates
// fp32 GEMM to ~2^-20.
// ---------------------------------------------------------------------------
__global__ __launch_bounds__(256) void k_prep(const float* __restrict__ W,
                                              unsigned short* __restrict__ wph,
                                              unsigned short* __restrict__ wpl,
                                              unsigned* __restrict__ emax_u) {
  const int gid = blockIdx.x * 256 + threadIdx.x;   // 512 blocks -> 131072
  if (gid == 0) *emax_u = 0u;
  const int k = gid >> 8;          // 0..511
  const int c = gid & 255;         // 0..255
  const float w = W[(size_t)k * F_OUT + c];
  const _Float16 hi = (_Float16)w;
  const _Float16 lo = (_Float16)(w - (float)hi);
  const size_t idx =
      (((size_t)(k >> 5) * 16 + (c >> 4)) * 64 + (c & 15) + 16 * ((k >> 3) & 3)) * 8 +
      (k & 7);
  wph[idx] = *(const unsigned short*)&hi;
  wpl[idx] = *(const unsigned short*)&lo;
}

// ---------------------------------------------------------------------------
// k_hgemm (r9, proven): h = x@W via split-f16 MFMA. Unchanged this round.
// ---------------------------------------------------------------------------
__global__ __launch_bounds__(512) void k_hgemm(const float* __restrict__ x,
                                               const uint4* __restrict__ wph4,
                                               const uint4* __restrict__ wpl4,
                                               const float* __restrict__ a,
                                               unsigned short* __restrict__ hpack,
                                               float* __restrict__ EI,
                                               float* __restrict__ EJ,
                                               unsigned* __restrict__ emax_u) {
  __shared__ float eip[4][32], ejp[4][32], emx[32];
  const int r0   = blockIdx.x * 32;
  const int tid  = threadIdx.x;
  const int wid  = tid >> 6, lane = tid & 63;
  const int mg   = wid >> 2, ng = wid & 3;      // 2 row-groups x 4 col-groups
  const int lo16 = lane & 15, hi4 = lane >> 4;

  const float* xrow = x + (size_t)(r0 + mg * 16 + lo16) * F_IN + hi4 * 8;
  const uint4* whb = wph4 + (size_t)(ng * 4) * 64 + lane;  // + (ks*16+nf)*64
  const uint4* wlb = wpl4 + (size_t)(ng * 4) * 64 + lane;

  f32x4 acc[4] = {};

  float4 xa = *(const float4*)(xrow);
  float4 xb = *(const float4*)(xrow + 4);
  uint4 wh[4], wl[4];
#pragma unroll
  for (int nf = 0; nf < 4; ++nf) {
    wh[nf] = whb[(size_t)nf * 64];
    wl[nf] = wlb[(size_t)nf * 64];
  }

#pragma unroll
  for (int ks = 0; ks < 16; ++ks) {
    H8U4 ah, al;
    const float v[8] = {xa.x, xa.y, xa.z, xa.w, xb.x, xb.y, xb.z, xb.w};
#pragma unroll
    for (int j = 0; j < 8; ++j) {
      const _Float16 h = (_Float16)v[j];
      ah.h[j] = h;
      al.h[j] = (_Float16)(v[j] - (float)h);
    }
    if (ks + 1 < 16) {
      xa = *(const float4*)(xrow + (ks + 1) * 32);
      xb = *(const float4*)(xrow + (ks + 1) * 32 + 4);
    }
#pragma unroll
    for (int nf = 0; nf < 4; ++nf) {
      H8U4 bh, bl;
      bh.u = wh[nf];
      bl.u = wl[nf];
      acc[nf] = __builtin_amdgcn_mfma_f32_16x16x32_f16(ah.h, bh.h, acc[nf], 0, 0, 0);
      acc[nf] = __builtin_amdgcn_mfma_f32_16x16x32_f16(al.h, bh.h, acc[nf], 0, 0, 0);
      acc[nf] = __builtin_amdgcn_mfma_f32_16x16x32_f16(ah.h, bl.h, acc[nf], 0, 0, 0);
    }
    if (ks + 1 < 16) {
#pragma unroll
      for (int nf = 0; nf < 4; ++nf) {
        wh[nf] = whb[(size_t)((ks + 1) * 16 + nf) * 64];
        wl[nf] = wlb[(size_t)((ks + 1) * 16 + nf) * 64];
      }
    }
  }

  float asv[4], adv[4];
#pragma unroll
  for (int nf = 0; nf < 4; ++nf) {
    const int c = ng * 64 + nf * 16 + lo16;
    asv[nf] = a[c];
    adv[nf] = a[F_OUT + c];
  }
#pragma unroll
  for (int q = 0; q < 4; ++q) {
    float s1 = acc[0][q] * asv[0] + acc[1][q] * asv[1] + acc[2][q] * asv[2] +
               acc[3][q] * asv[3];
    float s2 = acc[0][q] * adv[0] + acc[1][q] * adv[1] + acc[2][q] * adv[2] +
               acc[3][q] * adv[3];
#pragma unroll
    for (int o = 1; o < 16; o <<= 1) {
      s1 += __shfl_xor(s1, o);
      s2 += __shfl_xor(s2, o);
    }
    if (lo16 == 0) {
      const int rl = mg * 16 + hi4 * 4 + q;
      eip[ng][rl] = s1;
      ejp[ng][rl] = s2;
    }
  }

#pragma unroll
  for (int nf = 0; nf < 4; ++nf) {
#pragma unroll
    for (int q = 0; q < 4; ++q) {
      const int row = r0 + mg * 16 + hi4 * 4 + q;
      const int col = ng * 64 + nf * 16 + lo16;
      const size_t idx =
          (((size_t)(row >> 5) * 16 + (col >> 4)) * 64 + (col & 15) +
           16 * ((row >> 3) & 3)) * 8 + (row & 7);
      const _Float16 hv = (_Float16)acc[nf][q];
      hpack[idx] = *(const unsigned short*)&hv;
    }
  }

  __syncthreads();
  if (tid < 32) {
    const float s1 = eip[0][tid] + eip[1][tid] + eip[2][tid] + eip[3][tid];
    const float s2 = ejp[0][tid] + ejp[1][tid] + ejp[2][tid] + ejp[3][tid];
    const int row = r0 + tid;
    EI[row] = s1 * LOG2E;
    const float e2 = s2 * LOG2E;
    EJ[row] = e2;
    emx[tid] = e2;
  }
  __syncthreads();
  if (tid == 0) {
    float m = emx[0];
#pragma unroll
    for (int i = 1; i < 32; ++i) m = fmaxf(m, emx[i]);
    unsigned b = __float_as_uint(m);
    unsigned u = (b & 0x80000000u) ? ~b : (b | 0x80000000u);
    atomicMax(emax_u, u);
  }
}

// ---------------------------------------------------------------------------
// k_pv r15: NO P-exchange. R7 counters (MfmaUtil 8%, VALUBusy 16%, HBM 24%,
// 76% no-issue) showed the ps4 LDS round-trip + 2-barrier lockstep was the
// cost, not any pipe. Each wave now computes its own A-fragments IN REGISTER
// (4x redundant exp2 -- cheap at 16% VALUBusy): wave (mg,ng) computes
// P[mg*32+{lo,16+lo}][{hi*8..+8, 32+hi*8..+8}] = exactly its a00/a10/a01/a11.
// ps4 (8KB) + its write/drain/read + one barrier are deleted. Only the 512B
// bml mask buffer needs sync: 1 raw s_barrier + lgkmcnt per tile (waves stay
// within 1 tile -> parity-2 buffer safe). Fused coalesced adj->mask staging
// and depth-2 prefetch kept from proven r12 (KVBLK=64, nsplit=4).
// den: per-row LDS atomics from ng==0 waves only (no double count).
// ---------------------------------------------------------------------------
__global__ __launch_bounds__(512, 4) void k_pv(const int* __restrict__ adj,
                                               const uint4* __restrict__ hp4,
                                               const float* __restrict__ EI,
                                               const float* __restrict__ EJ,
                                               const unsigned* __restrict__ emax_u,
                                               float* __restrict__ npart,
                                               float* __restrict__ dpart,
                                               int ntiles) {
  __shared__ float ejhi[2048];                  // split's EJ (32 tiles x 64)
  __shared__ float A1[64], A2[64], den[64];
  __shared__ unsigned char bml[2][512];         // double-buffered mask bytes
  const int rowbase = blockIdx.x * 64;
  const int split   = blockIdx.y;
  const int jt0     = split * ntiles;
  const int tid     = threadIdx.x;
  const int wid  = tid >> 6, lane = tid & 63;
  const int lo   = lane & 15, hi = lane >> 4;

  float EMAX;
  {
    const unsigned u = *emax_u;
    EMAX = (u & 0x80000000u) ? __uint_as_float(u & 0x7fffffffu) : __uint_as_float(~u);
  }
  if (tid < 64) {
    const float e  = EI[rowbase + tid];
    const float s  = e + EMAX;
    const float mi = fmaxf(s, 0.2f * s);
    A1[tid] = e - mi;
    A2[tid] = 0.2f * e - mi;
    den[tid] = 0.f;
  }
  const bool uselds = (ntiles <= 32);
  if (uselds) {
    int eidx = jt0 * 64 + tid * 4;              // clamp guard
    if (eidx > N_NODES - 4) eidx = N_NODES - 4;
    *(float4*)&ejhi[tid * 4] = *(const float4*)&EJ[eidx];
  }

  // ---- adj staging role (unchanged r12): thread -> (row tid>>3, byte tid&7)
  const int arow = tid >> 3;
  const int* aadj = adj + (size_t)(rowbase + arow) * N_NODES + jt0 * 64 + (tid & 7) * 8;
  {
    const i32x4 v0 = __builtin_nontemporal_load((const i32x4*)(aadj));
    const i32x4 v1 = __builtin_nontemporal_load((const i32x4*)(aadj + 4));
    unsigned by = (v0.x > 0) | ((v0.y > 0) << 1) | ((v0.z > 0) << 2) |
                  ((v0.w > 0) << 3) | ((v1.x > 0) << 4) | ((v1.y > 0) << 5) |
                  ((v1.z > 0) << 6) | ((v1.w > 0) << 7);
    bml[0][tid] = (unsigned char)by;
  }
  i32x4 av0 = {0, 0, 0, 0}, av1 = {0, 0, 0, 0};
  if (ntiles > 1) {
    av0 = __builtin_nontemporal_load((const i32x4*)(aadj + 64));
    av1 = __builtin_nontemporal_load((const i32x4*)(aadj + 68));
  }
  __syncthreads();   // A1/A2, ejhi, bml[0] ready

  // ---- per-wave roles: wave (mg,ng), rows mg*32+{lo,16+lo} ----
  const int mg = wid >> 2, ng = wid & 3;
  const int r0l = mg * 32 + lo, r1l = r0l + 16;
  const float a1r0 = A1[r0l], a2r0 = A2[r0l];
  const float a1r1 = A1[r1l], a2r1 = A2[r1l];
  const int mb_r0 = r0l * 8, mb_r1 = r1l * 8;    // byte rows in bml
  const uint4* hb = hp4 + (ng * 4) * 64 + lane;
  const float* ejg = EJ + jt0 * 64;              // fallback path

  f32x4 acc[2][4] = {};
  float dacc0 = 0.f, dacc1 = 0.f;

  for (int jt = 0; jt < ntiles; ++jt) {
    const int tb = (jt0 + jt) * 2048;  // uint4 offset of this tile's first k-block
    // B fragments (L2/L3-hot; latency covered by the P compute below).
    const uint4 b00 = hb[tb + 0 * 1024 + 0 * 64];
    const uint4 b01 = hb[tb + 0 * 1024 + 1 * 64];
    const uint4 b02 = hb[tb + 0 * 1024 + 2 * 64];
    const uint4 b03 = hb[tb + 0 * 1024 + 3 * 64];
    const uint4 b10 = hb[tb + 1 * 1024 + 0 * 64];
    const uint4 b11 = hb[tb + 1 * 1024 + 1 * 64];
    const uint4 b12 = hb[tb + 1 * 1024 + 2 * 64];
    const uint4 b13 = hb[tb + 1 * 1024 + 3 * 64];

    // Mask bytes for this wave's 4 fragments (parity jt&1, written last tile).
    const unsigned m00 = bml[jt & 1][mb_r0 + hi];
    const unsigned m01 = bml[jt & 1][mb_r0 + 4 + hi];
    const unsigned m10 = bml[jt & 1][mb_r1 + hi];
    const unsigned m11 = bml[jt & 1][mb_r1 + 4 + hi];

    // EJ for j = hi*8..+8 (eh0) and 32+hi*8..+8 (eh1) -- LDS broadcast reads.
    float eh0[8], eh1[8];
    if (uselds) {
      const float4 h0 = *(const float4*)&ejhi[jt * 64 + hi * 8];
      const float4 h1 = *(const float4*)&ejhi[jt * 64 + hi * 8 + 4];
      const float4 h2 = *(const float4*)&ejhi[jt * 64 + 32 + hi * 8];
      const float4 h3 = *(const float4*)&ejhi[jt * 64 + 32 + hi * 8 + 4];
      eh0[0]=h0.x; eh0[1]=h0.y; eh0[2]=h0.z; eh0[3]=h0.w;
      eh0[4]=h1.x; eh0[5]=h1.y; eh0[6]=h1.z; eh0[7]=h1.w;
      eh1[0]=h2.x; eh1[1]=h2.y; eh1[2]=h2.z; eh1[3]=h2.w;
      eh1[4]=h3.x; eh1[5]=h3.y; eh1[6]=h3.z; eh1[7]=h3.w;
    } else {
      const float4 h0 = *(const float4*)(ejg + jt * 64 + hi * 8);
      const float4 h1 = *(const float4*)(ejg + jt * 64 + hi * 8 + 4);
      const float4 h2 = *(const float4*)(ejg + jt * 64 + 32 + hi * 8);
      const float4 h3 = *(const float4*)(ejg + jt * 64 + 32 + hi * 8 + 4);
      eh0[0]=h0.x; eh0[1]=h0.y; eh0[2]=h0.z; eh0[3]=h0.w;
      eh0[4]=h1.x; eh0[5]=h1.y; eh0[6]=h1.z; eh0[7]=h1.w;
      eh1[0]=h2.x; eh1[1]=h2.y; eh1[2]=h2.z; eh1[3]=h2.w;
      eh1[4]=h3.x; eh1[5]=h3.y; eh1[6]=h3.z; eh1[7]=h3.w;
    }

    // Build the wave's own A-fragments in-register (4x redundant exp2).
    auto mk = [&](const float* eh, unsigned m, float a1, float a2,
                  float& dac) -> uint4 {
      float p[8];
#pragma unroll
      for (int e = 0; e < 8; ++e) {
        const float s = fmaxf(eh[e] + a1, 0.2f * eh[e] + a2);
        const float v = __builtin_amdgcn_exp2f(s);
        p[e] = (m & (1u << e)) ? v : 0.f;
      }
      dac += ((p[0] + p[1]) + (p[2] + p[3])) + ((p[4] + p[5]) + (p[6] + p[7]));
      H2U q0, q1, q2, q3;
      q0.h = __builtin_amdgcn_cvt_pkrtz(p[0], p[1]);
      q1.h = __builtin_amdgcn_cvt_pkrtz(p[2], p[3]);
      q2.h = __builtin_amdgcn_cvt_pkrtz(p[4], p[5]);
      q3.h = __builtin_amdgcn_cvt_pkrtz(p[6], p[7]);
      uint4 r = {q0.u, q1.u, q2.u, q3.u};
      return r;
    };
    H8U4 a00, a10, a01, a11;
    a00.u = mk(eh0, m00, a1r0, a2r0, dacc0);
    a10.u = mk(eh0, m10, a1r1, a2r1, dacc1);
    a01.u = mk(eh1, m01, a1r0, a2r0, dacc0);
    a11.u = mk(eh1, m11, a1r1, a2r1, dacc1);

    // Pack mask bytes for tile jt+1 (regs from 2 tiles ago); issue NT adj
    // loads for tile jt+2 (stay in flight across the barrier; lgkm-only drain).
    if (jt + 1 < ntiles) {
      unsigned by = (av0.x > 0) | ((av0.y > 0) << 1) | ((av0.z > 0) << 2) |
                    ((av0.w > 0) << 3) | ((av1.x > 0) << 4) | ((av1.y > 0) << 5) |
                    ((av1.z > 0) << 6) | ((av1.w > 0) << 7);
      bml[(jt + 1) & 1][tid] = (unsigned char)by;
      if (jt + 2 < ntiles) {
        const int* ap = aadj + (jt + 2) * 64;
        av0 = __builtin_nontemporal_load((const i32x4*)ap);
        av1 = __builtin_nontemporal_load((const i32x4*)(ap + 4));
      }
    }

    // MFMA: operands fully register-resident (no LDS dependency).
    H8U4 b;
    __builtin_amdgcn_s_setprio(1);
    b.u = b00;
    acc[0][0] = __builtin_amdgcn_mfma_f32_16x16x32_f16(a00.h, b.h, acc[0][0], 0, 0, 0);
    acc[1][0] = __builtin_amdgcn_mfma_f32_16x16x32_f16(a10.h, b.h, acc[1][0], 0, 0, 0);
    b.u = b01;
    acc[0][1] = __builtin_amdgcn_mfma_f32_16x16x32_f16(a00.h, b.h, acc[0][1], 0, 0, 0);
    acc[1][1] = __builtin_amdgcn_mfma_f32_16x16x32_f16(a10.h, b.h, acc[1][1], 0, 0, 0);
    b.u = b02;
    acc[0][2] = __builtin_amdgcn_mfma_f32_16x16x32_f16(a00.h, b.h, acc[0][2], 0, 0, 0);
    acc[1][2] = __builtin_amdgcn_mfma_f32_16x16x32_f16(a10.h, b.h, acc[1][2], 0, 0, 0);
    b.u = b03;
    acc[0][3] = __builtin_amdgcn_mfma_f32_16x16x32_f16(a00.h, b.h, acc[0][3], 0, 0, 0);
    acc[1][3] = __builtin_amdgcn_mfma_f32_16x16x32_f16(a10.h, b.h, acc[1][3], 0, 0, 0);
    b.u = b10;
    acc[0][0] = __builtin_amdgcn_mfma_f32_16x16x32_f16(a01.h, b.h, acc[0][0], 0, 0, 0);
    acc[1][0] = __builtin_amdgcn_mfma_f32_16x16x32_f16(a11.h, b.h, acc[1][0], 0, 0, 0);
    b.u = b11;
    acc[0][1] = __builtin_amdgcn_mfma_f32_16x16x32_f16(a01.h, b.h, acc[0][1], 0, 0, 0);
    acc[1][1] = __builtin_amdgcn_mfma_f32_16x16x32_f16(a11.h, b.h, acc[1][1], 0, 0, 0);
    b.u = b12;
    acc[0][2] = __builtin_amdgcn_mfma_f32_16x16x32_f16(a01.h, b.h, acc[0][2], 0, 0, 0);
    acc[1][2] = __builtin_amdgcn_mfma_f32_16x16x32_f16(a11.h, b.h, acc[1][2], 0, 0, 0);
    b.u = b13;
    acc[0][3] = __builtin_amdgcn_mfma_f32_16x16x32_f16(a01.h, b.h, acc[0][3], 0, 0, 0);
    acc[1][3] = __builtin_amdgcn_mfma_f32_16x16x32_f16(a11.h, b.h, acc[1][3], 0, 0, 0);
    __builtin_amdgcn_s_setprio(0);

    // Single per-tile sync: bml[(jt+1)&1] writes visible; all waves done with
    // bml[jt&1] before tile jt+1 (whose pack overwrites parity (jt&1) at jt+2).
    asm volatile("s_waitcnt lgkmcnt(0)" ::: "memory");
    __builtin_amdgcn_s_barrier();
    asm volatile("" ::: "memory");
  }

  // den: ng==0 waves carry exactly one copy of each row's partial sums.
  if (ng == 0) {
    atomicAdd(&den[r0l], dacc0);
    atomicAdd(&den[r1l], dacc1);
  }
  __syncthreads();

  float* npb = npart + (size_t)split * N_NODES * F_OUT;
#pragma unroll
  for (int mi_ = 0; mi_ < 2; ++mi_) {
    const int rb = rowbase + (mg * 2 + mi_) * 16 + hi * 4;
#pragma unroll
    for (int nf = 0; nf < 4; ++nf) {
      const int col = ng * 64 + nf * 16 + lo;
#pragma unroll
      for (int r2 = 0; r2 < 4; ++r2)
        __builtin_nontemporal_store(acc[mi_][nf][r2],
                                    &npb[(size_t)(rb + r2) * F_OUT + col]);
    }
  }
  if (tid < 64)
    __builtin_nontemporal_store(den[tid],
                                &dpart[(size_t)split * N_NODES + rowbase + tid]);
}

// ---------------------------------------------------------------------------
// k_fin: combine splits, divide by denom, ELU, write output.
// ---------------------------------------------------------------------------
__global__ __launch_bounds__(256) void k_fin(const float* __restrict__ npart,
                                             const float* __restrict__ dpart,
                                             float* __restrict__ out,
                                             int nsplit) {
  const int gid = blockIdx.x * 256 + threadIdx.x;
  const int row = gid >> 6;
  const int c4  = (gid & 63) << 2;
  f32x4 s = {0.f, 0.f, 0.f, 0.f};
  float d = 0.f;
  for (int sp = 0; sp < nsplit; ++sp) {
    const f32x4 v = __builtin_nontemporal_load(
        (const f32x4*)(npart + ((size_t)sp * N_NODES + row) * F_OUT + c4));
    s += v;
    d += dpart[(size_t)sp * N_NODES + row];
  }
  const float inv = 1.f / d;
  float o[4] = {s.x * inv, s.y * inv, s.z * inv, s.w * inv};
#pragma unroll
  for (int i = 0; i < 4; ++i) o[i] = (o[i] > 0.f) ? o[i] : expm1f(o[i]);
  float4 ov = {o[0], o[1], o[2], o[3]};
  *(float4*)(out + (size_t)row * F_OUT + c4) = ov;
}

// ---------------------------------------------------------------------------
extern "C" void kernel_launch(void* const* d_in, const int* in_sizes, int n_in,
                              void* d_out, int out_size, void* d_ws, size_t ws_size,
                              hipStream_t stream) {
  const float* x   = (const float*)d_in[0];
  const int*   adj = (const int*)d_in[1];
  const float* W   = (const float*)d_in[2];
  const float* a   = (const float*)d_in[3];
  float* out = (float*)d_out;
  char*  ws  = (char*)d_ws;

  unsigned short* hpack = (unsigned short*)ws;  // 4 MB, B-fragment layout
  size_t off = (size_t)4 * 1024 * 1024;
  float* EI = (float*)(ws + off); off += (size_t)N_NODES * 4;
  float* EJ = (float*)(ws + off); off += (size_t)N_NODES * 4;
  unsigned* emax_u = (unsigned*)(ws + off); off += 256;
  float* dpart = (float*)(ws + off); off += (size_t)8 * N_NODES * 4;
  unsigned short* wph = (unsigned short*)(ws + off); off += (size_t)F_IN * F_OUT * 2;
  unsigned short* wpl = (unsigned short*)(ws + off); off += (size_t)F_IN * F_OUT * 2;
  float* npart = (float*)(ws + off);

  // r15: KVBLK=64, nsplit=4 (proven base); k_pv exchange-free.
  int nsplit = 4;
  while (nsplit > 1 && off + (size_t)nsplit * N_NODES * F_OUT * 4 > ws_size) nsplit >>= 1;

  k_prep<<<dim3((F_IN * F_OUT) / 256), dim3(256), 0, stream>>>(W, wph, wpl, emax_u);
  k_hgemm<<<dim3(N_NODES / 32), dim3(512), 0, stream>>>(
      x, (const uint4*)wph, (const uint4*)wpl, a, hpack, EI, EJ, emax_u);
  k_pv<<<dim3(128, nsplit), dim3(512), 0, stream>>>(adj, (const uint4*)hpack, EI, EJ,
                                                    emax_u, npart, dpart, 128 / nsplit);
  k_fin<<<dim3(N_NODES * 64 / 256), dim3(256), 0, stream>>>(npart, dpart, out, nsplit);
}